// Round 2
// baseline (93.602 us; speedup 1.0000x reference)
//
#include <hip/hip_runtime.h>

#define T_STEPS 151
#define NN 1024
#define DD 128
#define TILE 32
#define NTILE (NN / TILE)                    // 32
#define NBLOCKS (NTILE * (NTILE + 1) / 2)    // 528 upper-triangle tile pairs
#define LDSTRIDE 132                         // 16B-aligned rows
#define WSROW 304                            // per-block ws row (151+151+1, padded)
#define NPAIRS 523776.0f                     // 1024*1023/2

// ws layout: block b owns floats [b*304 .. b*304+303]:
//   [0..150] pos hist, [151..301] neg hist, [302] pos count, [303] pad

__global__ __launch_bounds__(256) void hist_kernel(
    const float* __restrict__ F, const int* __restrict__ cls, float* __restrict__ ws)
{
    __shared__ float As[TILE][LDSTRIDE];
    __shared__ float Bs[TILE][LDSTRIDE];
    __shared__ float hpos[T_STEPS];
    __shared__ float hneg[T_STEPS];
    __shared__ int   clsA[TILE];
    __shared__ int   clsB[TILE];
    __shared__ float pcount;

    const int t = threadIdx.x;

    // linear block id -> (bi, bj), bi <= bj
    int rem = blockIdx.x;
    int bi = 0;
    while (rem >= (NTILE - bi)) { rem -= (NTILE - bi); ++bi; }
    const int bj = bi + rem;

    for (int k = t; k < T_STEPS; k += 256) { hpos[k] = 0.f; hneg[k] = 0.f; }
    if (t == 0) pcount = 0.f;
    if (t < TILE)            clsA[t]        = cls[bi * TILE + t];
    else if (t < 2 * TILE)   clsB[t - TILE] = cls[bj * TILE + (t - TILE)];

    const float* Abase = F + (size_t)bi * TILE * DD;
    const float* Bbase = F + (size_t)bj * TILE * DD;
    for (int idx = t; idx < TILE * DD / 4; idx += 256) {
        int r = idx >> 5;
        int c = (idx & 31) << 2;
        *(float4*)&As[r][c] = *(const float4*)(Abase + r * DD + c);
        *(float4*)&Bs[r][c] = *(const float4*)(Bbase + r * DD + c);
    }
    __syncthreads();

    // 2x2 micro-tile: rows {r2, r2+16} x cols {c2, c2+16}
    const int r2 = t >> 4;   // 0..15
    const int c2 = t & 15;   // 0..15

    float acc[2][2][4];
    #pragma unroll
    for (int a = 0; a < 2; ++a)
        #pragma unroll
        for (int b = 0; b < 2; ++b)
            #pragma unroll
            for (int q = 0; q < 4; ++q) acc[a][b][q] = 0.f;

    #pragma unroll 4
    for (int k = 0; k < DD; k += 4) {
        float4 a0 = *(const float4*)&As[r2][k];
        float4 a1 = *(const float4*)&As[r2 + 16][k];
        float4 b0 = *(const float4*)&Bs[c2][k];
        float4 b1 = *(const float4*)&Bs[c2 + 16][k];
        acc[0][0][0] += a0.x * b0.x; acc[0][0][1] += a0.y * b0.y;
        acc[0][0][2] += a0.z * b0.z; acc[0][0][3] += a0.w * b0.w;
        acc[0][1][0] += a0.x * b1.x; acc[0][1][1] += a0.y * b1.y;
        acc[0][1][2] += a0.z * b1.z; acc[0][1][3] += a0.w * b1.w;
        acc[1][0][0] += a1.x * b0.x; acc[1][0][1] += a1.y * b0.y;
        acc[1][0][2] += a1.z * b0.z; acc[1][0][3] += a1.w * b0.w;
        acc[1][1][0] += a1.x * b1.x; acc[1][1][1] += a1.y * b1.y;
        acc[1][1][2] += a1.z * b1.z; acc[1][1][3] += a1.w * b1.w;
    }

    const float STEP = 2.0f / 150.0f;
    float myp = 0.f;
    {
        // Bit-exact replication of the reference's fp32 binning: no FMA
        // contraction, true divisions. delta==t equality must not flip.
        #pragma clang fp contract(off)
        #pragma unroll
        for (int ii = 0; ii < 2; ++ii) {
            #pragma unroll
            for (int jj = 0; jj < 2; ++jj) {
                int gi = bi * TILE + r2 + 16 * ii;
                int gj = bj * TILE + c2 + 16 * jj;
                if (gi < gj) {
                    float* a = acc[ii][jj];
                    float s = (a[0] + a[1]) + (a[2] + a[3]);
                    bool eqf = (clsA[r2 + 16 * ii] == clsB[c2 + 16 * jj]);
                    float kf    = floorf((s + 1.0f) / STEP);
                    float delta = kf * STEP - 1.0f;
                    int   kk    = (int)kf;
                    if (kk >= 0 && kk < T_STEPS) {
                        float tk = -1.0f + (float)kk * STEP;
                        if (delta == tk) {                   // indsb
                            float wb = (-s + tk + STEP) / STEP;
                            atomicAdd(eqf ? &hpos[kk] : &hneg[kk], wb);
                        }
                    }
                    int k1 = kk + 1;
                    if (k1 >= 0 && k1 < T_STEPS) {
                        float tk1 = -1.0f + (float)k1 * STEP;
                        if (delta == (tk1 - STEP)) {         // indsa
                            float wa = (s - tk1 + STEP) / STEP;
                            atomicAdd(eqf ? &hpos[k1] : &hneg[k1], wa);
                        }
                    }
                    if (eqf) myp += 1.f;
                }
            }
        }
    }
    atomicAdd(&pcount, myp);
    __syncthreads();

    // private ws row per block: no pre-zero, no global atomics
    float* base = ws + (size_t)blockIdx.x * WSROW;
    for (int k = t; k < WSROW; k += 256) {
        float v = (k < T_STEPS)     ? hpos[k]
                : (k < 2 * T_STEPS) ? hneg[k - T_STEPS]
                : (k == 2 * T_STEPS)? pcount : 0.f;
        base[k] = v;
    }
}

__global__ __launch_bounds__(1024) void final_kernel(
    const float* __restrict__ ws, float* __restrict__ out)
{
    __shared__ float part[3][WSROW];
    __shared__ float hp[T_STEPS], hn[T_STEPS];
    __shared__ float poss;
    const int t = threadIdx.x;

    if (t < 3 * WSROW) {                 // 912 active
        const int j = t % WSROW;
        const int g = t / WSROW;         // 0..2
        float s = 0.f;
        #pragma unroll 4
        for (int b = g; b < NBLOCKS; b += 3) s += ws[(size_t)b * WSROW + j];
        part[g][j] = s;
    }
    __syncthreads();
    if (t < WSROW) {
        float v = part[0][t] + part[1][t] + part[2][t];
        if (t < T_STEPS)            hp[t] = v;
        else if (t < 2 * T_STEPS)   hn[t - T_STEPS] = v;
        else if (t == 2 * T_STEPS)  poss = v;
    }
    __syncthreads();
    if (t == 0) {
        #pragma clang fp contract(off)
        float pos = poss;
        float neg = NPAIRS - pos;
        float cdf = 0.f, loss = 0.f;
        for (int j = 0; j < T_STEPS; ++j) {
            cdf  += hp[j] / pos;
            loss += (hn[j] / neg) * cdf;
        }
        *out = loss;
    }
}

extern "C" void kernel_launch(void* const* d_in, const int* in_sizes, int n_in,
                              void* d_out, int out_size, void* d_ws, size_t ws_size,
                              hipStream_t stream)
{
    const float* F   = (const float*)d_in[0];
    const int*   cls = (const int*)d_in[1];
    float*       ws  = (float*)d_ws;
    float*       out = (float*)d_out;

    hist_kernel<<<NBLOCKS, 256, 0, stream>>>(F, cls, ws);
    final_kernel<<<1, 1024, 0, stream>>>(ws, out);
}